// Round 1
// baseline (243.436 us; speedup 1.0000x reference)
//
#include <hip/hip_runtime.h>

// Y_t = U^T * X_t * V  per token, via bf16 MFMA 16x16x32.
// Stage 1: T = X @ V   (A = X from LDS, B = V fragments from global swizzled)
// Stage 2: Y = U^T @ T (A = U^T fragments from global swizzled, B = T^T from LDS)

typedef short bf16x8 __attribute__((ext_vector_type(8)));
typedef float f32x4  __attribute__((ext_vector_type(4)));

#define DIM    128
#define PITCH  136   // bf16 elements per LDS row (pad 8 -> 16B, spreads banks)
#define NTOK   2048

static __device__ __forceinline__ unsigned short f2bf(float f) {
    union { float f; unsigned u; } v; v.f = f;
    unsigned r = v.u + 0x7FFFu + ((v.u >> 16) & 1u);  // round-nearest-even
    return (unsigned short)(r >> 16);
}

// Build U/V bf16 fragment-swizzled copies in workspace.
// Granule g in [0,2048) per matrix: g = (tile*4 + kk)*64 + lane.
// Granule holds 8 bf16: B[k][n] = src[k*128 + n] for n = tile*16 + (lane&15),
// k = kk*32 + (lane>>4)*8 + j, j=0..7. (For U this yields A[m=j1][k=i1] = U[i1*128+j1].)
__global__ void kron_prep_uv(const float* __restrict__ U,
                             const float* __restrict__ V,
                             unsigned short* __restrict__ swz) {
    int g = blockIdx.x * blockDim.x + threadIdx.x;   // 0..4095
    const float* src = (g < 2048) ? V : U;
    int gg   = g & 2047;
    int lane = gg & 63;
    int blk  = gg >> 6;
    int kk   = blk & 3;
    int tile = blk >> 2;
    int n  = tile * 16 + (lane & 15);
    int k0 = kk * 32 + (lane >> 4) * 8;
    bf16x8 v;
#pragma unroll
    for (int j = 0; j < 8; ++j)
        v[j] = (short)f2bf(src[(k0 + j) * DIM + n]);
    *(bf16x8*)(swz + (size_t)g * 8) = v;
}

__global__ __launch_bounds__(256, 4)
void kron_main(const float* __restrict__ x,
               const unsigned short* __restrict__ Vs,   // swizzled V (stage-1 B frags)
               const unsigned short* __restrict__ Us,   // swizzled U^T (stage-2 A frags)
               float* __restrict__ y) {
    __shared__ unsigned short lds[DIM * PITCH];  // 34816 B: X_t (bf16), then T^T (bf16)

    const int t    = blockIdx.x;
    const int tid  = threadIdx.x;
    const int lane = tid & 63;
    const int wave = tid >> 6;
    const int m16  = lane & 15;
    const int q    = lane >> 4;
    const int r0   = (wave >> 1) * 64;   // row quadrant (i1 for stage1, j1 for stage2)
    const int c0   = (wave & 1) * 64;    // col quadrant (j2)

    // ---- load X_t (fp32) -> bf16 LDS, row-major pitch 136 ----
    {
        const float* xp   = x + (size_t)t * (DIM * DIM);
        const int    col8 = (tid & 15) * 8;
        const int    rb   = tid >> 4;          // 0..15
#pragma unroll
        for (int it = 0; it < 8; ++it) {
            int i1 = it * 16 + rb;
            const float4 a = *(const float4*)(xp + i1 * DIM + col8);
            const float4 b = *(const float4*)(xp + i1 * DIM + col8 + 4);
            bf16x8 v;
            v[0] = (short)f2bf(a.x); v[1] = (short)f2bf(a.y);
            v[2] = (short)f2bf(a.z); v[3] = (short)f2bf(a.w);
            v[4] = (short)f2bf(b.x); v[5] = (short)f2bf(b.y);
            v[6] = (short)f2bf(b.z); v[7] = (short)f2bf(b.w);
            *(bf16x8*)&lds[i1 * PITCH + col8] = v;
        }
    }
    __syncthreads();

    // ---- stage 1: T = X @ V ----
    f32x4 acc[4][4] = {};
#pragma unroll
    for (int kk = 0; kk < 4; ++kk) {
        bf16x8 bfrag[4];
#pragma unroll
        for (int nt = 0; nt < 4; ++nt)
            bfrag[nt] = *(const bf16x8*)(Vs + (size_t)(((c0 / 16 + nt) * 4 + kk) * 64 + lane) * 8);
#pragma unroll
        for (int mt = 0; mt < 4; ++mt) {
            bf16x8 af = *(const bf16x8*)&lds[(r0 + mt * 16 + m16) * PITCH + kk * 32 + q * 8];
#pragma unroll
            for (int nt = 0; nt < 4; ++nt)
                acc[mt][nt] = __builtin_amdgcn_mfma_f32_16x16x32_bf16(af, bfrag[nt], acc[mt][nt], 0, 0, 0);
        }
    }
    __syncthreads();   // everyone done reading X from LDS

    // ---- write T^T (bf16) into the same LDS: Tt[j2][i1], pitch 136 ----
    // C-layout: col j2 = tile_col + m16, rows i1 = tile_row + q*4 + r  -> 4 contiguous bf16.
#pragma unroll
    for (int mt = 0; mt < 4; ++mt) {
#pragma unroll
        for (int nt = 0; nt < 4; ++nt) {
            int j2 = c0 + nt * 16 + m16;
            int i1 = r0 + mt * 16 + q * 4;
            unsigned p0 = (unsigned)f2bf(acc[mt][nt][0]) | ((unsigned)f2bf(acc[mt][nt][1]) << 16);
            unsigned p1 = (unsigned)f2bf(acc[mt][nt][2]) | ((unsigned)f2bf(acc[mt][nt][3]) << 16);
            uint2 w; w.x = p0; w.y = p1;
            *(uint2*)&lds[j2 * PITCH + i1] = w;
        }
    }
    __syncthreads();

    // ---- stage 2: Y = U^T @ T ----
    f32x4 acc2[4][4] = {};
#pragma unroll
    for (int kk = 0; kk < 4; ++kk) {
        bf16x8 afrag[4];
#pragma unroll
        for (int mt = 0; mt < 4; ++mt)
            afrag[mt] = *(const bf16x8*)(Us + (size_t)(((r0 / 16 + mt) * 4 + kk) * 64 + lane) * 8);
#pragma unroll
        for (int nt = 0; nt < 4; ++nt) {
            bf16x8 bf = *(const bf16x8*)&lds[(c0 + nt * 16 + m16) * PITCH + kk * 32 + q * 8];
#pragma unroll
            for (int mt = 0; mt < 4; ++mt)
                acc2[mt][nt] = __builtin_amdgcn_mfma_f32_16x16x32_bf16(afrag[mt], bf, acc2[mt][nt], 0, 0, 0);
        }
    }

    // ---- store Y (fp32) ----
    float* yp = y + (size_t)t * (DIM * DIM);
#pragma unroll
    for (int mt = 0; mt < 4; ++mt) {
#pragma unroll
        for (int nt = 0; nt < 4; ++nt) {
            int j2 = c0 + nt * 16 + m16;
            int j1 = r0 + mt * 16 + q * 4;
#pragma unroll
            for (int r = 0; r < 4; ++r)
                yp[(j1 + r) * DIM + j2] = acc2[mt][nt][r];
        }
    }
}

extern "C" void kernel_launch(void* const* d_in, const int* in_sizes, int n_in,
                              void* d_out, int out_size, void* d_ws, size_t ws_size,
                              hipStream_t stream) {
    const float* x = (const float*)d_in[0];
    const float* U = (const float*)d_in[1];
    const float* V = (const float*)d_in[2];
    float*       y = (float*)d_out;

    unsigned short* swz = (unsigned short*)d_ws;   // [0,16384): V frags; [16384,32768): U frags
    kron_prep_uv<<<16, 256, 0, stream>>>(U, V, swz);
    kron_main<<<NTOK, 256, 0, stream>>>(x, swz, swz + 2048 * 8, y);
}